// Round 10
// baseline (1241.043 us; speedup 1.0000x reference)
//
#include <hip/hip_runtime.h>
#include <hip/hip_bf16.h>
#include <hip/hip_fp16.h>
#include <math.h>

typedef __hip_bfloat16 bf16;
typedef __attribute__((ext_vector_type(8))) short short8;
typedef __attribute__((ext_vector_type(4))) float f32x4;

#define NATT 11
#define Bb 8
#define Ss 512
#define Dd 768
#define Hh 256
#define WSLICE 589824L  // 768*768

__device__ __forceinline__ void stf(float* p, float v) { *p = v; }
__device__ __forceinline__ void stf(bf16* p, float v) { *p = __float2bfloat16(v); }

__device__ __forceinline__ float blo(unsigned u) { return __uint_as_float(u << 16); }
__device__ __forceinline__ float bhi(unsigned u) { return __uint_as_float(u & 0xffff0000u); }
__device__ __forceinline__ float b2f(unsigned short u) { return __uint_as_float(((unsigned)u) << 16); }

__device__ __forceinline__ float ldg_any(const void* base, long idx, int flag) {
  if (flag) return ((const float*)base)[idx];
  return __bfloat162float(((const bf16*)base)[idx]);
}

__device__ __forceinline__ unsigned packh2(float a, float b) {
  __half2 hh = __floats2half2_rn(a, b);
  return __builtin_bit_cast(unsigned, hh);
}
__device__ __forceinline__ unsigned short f2h(float v) {
  __half h = __float2half(v);
  return __builtin_bit_cast(unsigned short, h);
}

typedef _Float16 f16x2 __attribute__((ext_vector_type(2)));

__device__ __forceinline__ float dot2u(unsigned a, unsigned b, float c) {
#if __has_builtin(__builtin_amdgcn_fdot2)
  return __builtin_amdgcn_fdot2(__builtin_bit_cast(f16x2, a),
                                __builtin_bit_cast(f16x2, b), c, false);
#else
  __half2 ah = __builtin_bit_cast(__half2, a);
  __half2 bh = __builtin_bit_cast(__half2, b);
  float2 af = __half22float2(ah), bf = __half22float2(bh);
  return c + af.x * bf.x + af.y * bf.y;
#endif
}

// sum across a lane-quad using DPP quad_perm (VALU only, no LDS)
__device__ __forceinline__ float quad_sum(float v) {
#if __has_builtin(__builtin_amdgcn_update_dpp)
  int y = __builtin_amdgcn_update_dpp(0, __builtin_bit_cast(int, v), 0xB1, 0xF, 0xF, true);
  v += __builtin_bit_cast(float, y);
  y = __builtin_amdgcn_update_dpp(0, __builtin_bit_cast(int, v), 0x4E, 0xF, 0xF, true);
  v += __builtin_bit_cast(float, y);
  return v;
#else
  v += __shfl_xor(v, 1);
  v += __shfl_xor(v, 2);
  return v;
#endif
}

// barrier that drains ONLY LDS (lgkmcnt) — leaves global prefetches in flight.
__device__ __forceinline__ void lds_barrier() {
  asm volatile("s_waitcnt lgkmcnt(0)\n\ts_barrier" ::: "memory");
}

__device__ __forceinline__ void load_lds16(const void* g, void* l) {
  __builtin_amdgcn_global_load_lds(
      (const __attribute__((address_space(1))) unsigned int*)g,
      (__attribute__((address_space(3))) unsigned int*)l, 16, 0, 0);
}

// ---------- dtype probe ----------
__global__ __launch_bounds__(64) void probe_kernel(
    const unsigned short* __restrict__ sequ, const unsigned* __restrict__ labu,
    int* __restrict__ flags)
{
  int t = threadIdx.x;
  int wild = 0;
#pragma unroll
  for (int i = 0; i < 4; i++) {
    unsigned short v = sequ[t + i * 64];
    int e = (v >> 7) & 0xFF;
    if (e < 90 || e > 160) wild++;
  }
  int nzodd = 0;
#pragma unroll
  for (int i = 0; i < 2; i++) {
    unsigned w = labu[(t + i * 64) * 2 + 1];
    if (w != 0) nzodd++;
  }
  for (int o = 32; o > 0; o >>= 1) {
    wild  += __shfl_down(wild, o);
    nzodd += __shfl_down(nzodd, o);
  }
  if (t == 0) {
    flags[0] = (wild > 32) ? 1 : 0;
    flags[1] = (nzodd == 0) ? 1 : 0;
  }
}

// ---------- seq -> bf16 ----------
__global__ __launch_bounds__(256) void conv_seq_kernel(
    const void* __restrict__ seq, bf16* __restrict__ seqb,
    const int* __restrict__ flags)
{
  int flag = flags[0];
  long row = blockIdx.x;
#pragma unroll
  for (int i = 0; i < 3; i++) {
    long e = row * Dd + threadIdx.x + i * 256;
    seqb[e] = __float2bfloat16(ldg_any(seq, e, flag));
  }
}

// ---------- generic convert to bf16 (Wih) ----------
__global__ __launch_bounds__(256) void convert_kernel(
    const void* __restrict__ src, bf16* __restrict__ dst, long n,
    const int* __restrict__ flags)
{
  int flag = flags[0];
  long i = (long)blockIdx.x * 256 + threadIdx.x;
  if (i < n) dst[i] = __float2bfloat16(ldg_any(src, i, flag));
}

// ---------- Qsmall[11][7][768] = relu(emb7 @ Wq + bq); grid (12, 11) ----------
// 64-col blocks with 4-way K split: 132 blocks, ~196KB traffic each.
__global__ __launch_bounds__(256) void smalls_kernel(
    const void* __restrict__ emb, const void* __restrict__ Wq,
    const void* __restrict__ bq, float* __restrict__ Qsmall,
    const int* __restrict__ flags)
{
  int flag = flags[0];
  __shared__ float embsh[7 * 768];
  __shared__ float psum[4][7][64];
  int z = blockIdx.y;   // branch
  int bx = blockIdx.x;  // n-chunk of 64
  int tid = threadIdx.x;
  int sub = tid >> 6, nl = tid & 63;
  for (int i = tid; i < 7 * 768; i += 256) embsh[i] = ldg_any(emb, i, flag);
  __syncthreads();
  int n = bx * 64 + nl;
  long base = (long)z * WSLICE;
  float acc[7] = {};
  int e0 = sub * 192;
  for (int e = e0; e < e0 + 192; e++) {
    float wv = ldg_any(Wq, base + (long)e * Dd + n, flag);
#pragma unroll
    for (int l = 0; l < 7; l++) acc[l] += embsh[l * 768 + e] * wv;
  }
#pragma unroll
  for (int l = 0; l < 7; l++) psum[sub][l][nl] = acc[l];
  __syncthreads();
  if (sub == 0) {
    float bv = ldg_any(bq, z * Dd + n, flag);
#pragma unroll
    for (int l = 0; l < 7; l++) {
      float v = psum[0][l][nl] + psum[1][l][nl] + psum[2][l][nl] + psum[3][l][nl] + bv;
      Qsmall[((long)z * 7 + l) * Dd + n] = fmaxf(v, 0.f);
    }
  }
}

// ---------- emb rows -> outsm[640+l] (bf16) + qmask7 ----------
__global__ __launch_bounds__(256) void emb_copy_kernel(
    const void* __restrict__ emb, bf16* __restrict__ outsm,
    float* __restrict__ qmask7, const int* __restrict__ flags)
{
  int flag = flags[0];
  int l = blockIdx.x;   // 0..6
  int t = threadIdx.x;
  float s = 0.f;
#pragma unroll
  for (int i = 0; i < 3; i++) {
    int e = t + i * 256;
    float v = ldg_any(emb, (long)l * Dd + e, flag);
    outsm[(long)(640 + l) * Dd + e] = __float2bfloat16(v);
    s += v;
  }
  for (int o = 32; o > 0; o >>= 1) s += __shfl_down(s, o);
  __shared__ float red[4];
  if ((t & 63) == 0) red[t >> 6] = s;
  __syncthreads();
  if (t == 0) {
    float tot = red[0] + red[1] + red[2] + red[3];
    qmask7[l] = (tot != 0.f) ? 1.f : 0.f;
  }
}

// ---------- transpose Wk/Wv branch slices to [N][K] bf16 ----------
__global__ __launch_bounds__(256) void transpose2_kernel(
    const void* __restrict__ Wk, const void* __restrict__ Wv,
    bf16* __restrict__ WT, const int* __restrict__ flags)
{
  int flag = flags[0];
  __shared__ float tile[32][33];
  int z = blockIdx.z;
  int m = z >> 1, wsel = z & 1;
  const void* src = wsel ? Wv : Wk;
  long off = (long)m * WSLICE;
  bf16* dst = WT + (long)z * WSLICE;
  int kk0 = blockIdx.y * 32, n0 = blockIdx.x * 32;
  int tx = threadIdx.x & 31, ty = threadIdx.x >> 5;
#pragma unroll
  for (int i = 0; i < 4; i++)
    tile[ty + i * 8][tx] = ldg_any(src, off + (long)(kk0 + ty + i * 8) * Dd + n0 + tx, flag);
  __syncthreads();
#pragma unroll
  for (int i = 0; i < 4; i++)
    dst[(long)(n0 + ty + i * 8) * Dd + kk0 + tx] = __float2bfloat16(tile[tx][ty + i * 8]);
}

// ---------- MFMA GEMM core: C = epi(scale*A@B^T) ----------
// cMode: 0=bf16, 2=fp32, 3=fp16, 4=fp16 transposed (C[col*ldC+row])
__device__ __forceinline__ void gemm_mfma_core(
    const bf16* __restrict__ Ab, long ldA,
    const bf16* __restrict__ Bbp, long ldB,
    bf16* As, bf16* Bs, int bm, int bn, int K,
    const void* bias, long bOff,
    void* C, long ldC, int cMode,
    float scale, int relu, int fflag)
{
  int tid = threadIdx.x;
  int lane = tid & 63, w = tid >> 6;
  int mo = (w & 1) * 64, no = (w >> 1) * 64;
  int l15 = lane & 15, q4 = lane >> 4;
  int gr = lane >> 2;
  int gs = (lane & 3) * 8;
  const bf16* aS0 = Ab + (long)(bm + w * 16 + gr) * ldA + gs;
  const bf16* aS1 = aS0 + 64 * ldA;
  const bf16* bS0 = Bbp + (long)(bn + w * 16 + gr) * ldB + gs;
  const bf16* bS1 = bS0 + 64 * ldB;
  bf16* aD0 = As + w * 512;
  bf16* aD1 = As + 2048 + w * 512;
  bf16* bD0 = Bs + w * 512;
  bf16* bD1 = Bs + 2048 + w * 512;

  f32x4 acc[4][4];
#pragma unroll
  for (int i = 0; i < 4; i++)
#pragma unroll
    for (int j = 0; j < 4; j++)
#pragma unroll
      for (int r = 0; r < 4; r++) acc[i][j][r] = 0.f;

  for (int k0 = 0; k0 < K; k0 += 32) {
    load_lds16(aS0, aD0);
    load_lds16(aS1, aD1);
    load_lds16(bS0, bD0);
    load_lds16(bS1, bD1);
    aS0 += 32; aS1 += 32; bS0 += 32; bS1 += 32;
    __syncthreads();   // needs vmcnt drain (global_load_lds) — keep full syncthreads
    short8 af[4], bfv[4];
#pragma unroll
    for (int i = 0; i < 4; i++)
      af[i] = *(const short8*)(As + (mo + i * 16 + l15) * 32 + q4 * 8);
#pragma unroll
    for (int j = 0; j < 4; j++)
      bfv[j] = *(const short8*)(Bs + (no + j * 16 + l15) * 32 + q4 * 8);
#pragma unroll
    for (int i = 0; i < 4; i++)
#pragma unroll
      for (int j = 0; j < 4; j++)
        acc[i][j] = __builtin_amdgcn_mfma_f32_16x16x32_bf16(af[i], bfv[j], acc[i][j], 0, 0, 0);
    __syncthreads();
  }

  float bsv[4];
#pragma unroll
  for (int j = 0; j < 4; j++) {
    int colg = bn + no + j * 16 + l15;
    bsv[j] = bias ? ldg_any(bias, bOff + colg, fflag) : 0.f;
  }
#pragma unroll
  for (int i = 0; i < 4; i++) {
#pragma unroll
    for (int j = 0; j < 4; j++) {
      int colg = bn + no + j * 16 + l15;
      if (cMode == 4) {
        int rowg0 = bm + mo + i * 16 + q4 * 4;
        ushort4 pk;
        unsigned short tmp[4];
#pragma unroll
        for (int r = 0; r < 4; r++) {
          float v = acc[i][j][r] * scale + bsv[j];
          if (relu) v = fmaxf(v, 0.f);
          tmp[r] = f2h(v);
        }
        pk.x = tmp[0]; pk.y = tmp[1]; pk.z = tmp[2]; pk.w = tmp[3];
        *(ushort4*)((unsigned short*)C + (long)colg * ldC + rowg0) = pk;
      } else {
#pragma unroll
        for (int r = 0; r < 4; r++) {
          int rowg = bm + mo + i * 16 + q4 * 4 + r;
          float v = acc[i][j][r] * scale + bsv[j];
          if (relu) v = fmaxf(v, 0.f);
          long off2 = (long)rowg * ldC + colg;
          if (cMode == 2)      ((float*)C)[off2] = v;
          else if (cMode == 3) ((unsigned short*)C)[off2] = f2h(v);
          else                 ((bf16*)C)[off2] = __float2bfloat16(v);
        }
      }
    }
  }
}

// ---------- K/V projections (fp16 out), z = m*2 + {0:K,1:V} ----------
__global__ __launch_bounds__(256, 2) void proj_kernel(
    const bf16* __restrict__ seqb, const bf16* __restrict__ WT,
    const void* __restrict__ bk, const void* __restrict__ bv,
    unsigned short* __restrict__ Kb, unsigned short* __restrict__ Vt,
    const int* __restrict__ flags)
{
  __shared__ __align__(16) bf16 As[4096];
  __shared__ __align__(16) bf16 Bs[4096];
  int z = blockIdx.z;
  int m = z >> 1, wsel = z & 1;
  const bf16* B = WT + (long)z * WSLICE;
  if (wsel == 0) {
    gemm_mfma_core(seqb, Dd, B, Dd, As, Bs, blockIdx.y * 128, blockIdx.x * 128, Dd,
                   bk, (long)m * Dd, Kb + (long)m * 4096 * Dd, Dd, 3, 1.f, 1, flags[0]);
  } else {
    gemm_mfma_core(seqb, Dd, B, Dd, As, Bs, blockIdx.y * 128, blockIdx.x * 128, Dd,
                   bv, (long)m * Dd, Vt + (long)m * Dd * 4096, 4096, 4, 1.f, 1, flags[0]);
  }
}

// ---------- seqW = seq @ Wih^T + bih (bf16), z = dir ----------
__global__ __launch_bounds__(256, 2) void seqw_kernel(
    const bf16* __restrict__ seqb, const bf16* __restrict__ WihB,
    const void* __restrict__ bih, bf16* __restrict__ seqW,
    const int* __restrict__ flags)
{
  __shared__ __align__(16) bf16 As[4096];
  __shared__ __align__(16) bf16 Bs[4096];
  int dir = blockIdx.z;
  gemm_mfma_core(seqb, Dd, WihB + (long)dir * WSLICE, Dd, As, Bs,
                 blockIdx.y * 128, blockIdx.x * 128, Dd,
                 bih, (long)dir * Dd, seqW + (long)dir * 4096 * Dd, Dd, 0,
                 1.f, 0, flags[0]);
}

// ---------- PVW = outsm(768 rows incl emb @640) @ Wih^T (fp32), z = dir ----------
__global__ __launch_bounds__(256, 2) void pvw_kernel(
    const bf16* __restrict__ outsm, const bf16* __restrict__ WihB,
    float* __restrict__ PVW, const int* __restrict__ flags)
{
  __shared__ __align__(16) bf16 As[4096];
  __shared__ __align__(16) bf16 Bs[4096];
  int dir = blockIdx.z;
  gemm_mfma_core(outsm, Dd, WihB + (long)dir * WSLICE, Dd, As, Bs,
                 blockIdx.y * 128, blockIdx.x * 128, Dd,
                 nullptr, 0, PVW + (long)dir * 768 * Dd, Dd, 2, 1.f, 0, flags[0]);
}

// ---------- fused scores+softmax+mask+PV per (k,b) ----------
__global__ __launch_bounds__(512, 2) void attn_kernel(
    const unsigned short* __restrict__ Kb, const unsigned short* __restrict__ Vt,
    const float* __restrict__ Qsmall, const float* __restrict__ qmask7,
    bf16* __restrict__ outsm, float scl)
{
  int blk = blockIdx.x;  // k*8+b
  int k = blk >> 3, b = blk & 7;
  int tid = threadIdx.x;
  int lane = tid & 63, w = tid >> 6;
  __shared__ unsigned qs[7][384];
  __shared__ unsigned short ash[7][512];
  __shared__ float wred[8][7];
  __shared__ float gred[7];
  __shared__ float finv[7];
  for (int i = tid; i < 7 * 384; i += 512) {
    int l = i / 384, e2 = i - l * 384;
    const float* qp = Qsmall + ((long)k * 7 + l) * Dd + 2 * e2;
    qs[l][e2] = packh2(qp[0], qp[1]);
  }
  __syncthreads();
  const uint4* Krow = (const uint4*)(Kb + ((long)k * 4096 + b * 512 + tid) * Dd);
  float sc[7] = {};
  for (int e8 = 0; e8 < 96; e8++) {
    uint4 kv = Krow[e8];
#pragma unroll
    for (int l = 0; l < 7; l++) {
      sc[l] = dot2u(qs[l][e8 * 4],     kv.x, sc[l]);
      sc[l] = dot2u(qs[l][e8 * 4 + 1], kv.y, sc[l]);
      sc[l] = dot2u(qs[l][e8 * 4 + 2], kv.z, sc[l]);
      sc[l] = dot2u(qs[l][e8 * 4 + 3], kv.w, sc[l]);
    }
  }
#pragma unroll
  for (int l = 0; l < 7; l++) sc[l] *= scl;
#pragma unroll
  for (int l = 0; l < 7; l++) {
    float v = sc[l];
    for (int o = 32; o > 0; o >>= 1) v = fmaxf(v, __shfl_down(v, o));
    if (lane == 0) wred[w][l] = v;
  }
  __syncthreads();
  if (tid < 7) {
    float m = wred[0][tid];
#pragma unroll
    for (int i = 1; i < 8; i++) m = fmaxf(m, wred[i][tid]);
    gred[tid] = m;
  }
  __syncthreads();
  float ev[7];
#pragma unroll
  for (int l = 0; l < 7; l++) {
    ev[l] = __expf(sc[l] - gred[l]);
    float v = ev[l];
    for (int o = 32; o > 0; o >>= 1) v += __shfl_down(v, o);
    if (lane == 0) wred[w][l] = v;
  }
  __syncthreads();
  if (tid < 7) {
    float s = 0.f;
#pragma unroll
    for (int i = 0; i < 8; i++) s += wred[i][tid];
    finv[tid] = qmask7[tid] / s;
  }
  __syncthreads();
#pragma unroll
  for (int l = 0; l < 7; l++) ash[l][tid] = f2h(ev[l] * finv[l]);
  __syncthreads();
  for (int rep = 0; rep < 2; rep++) {
    int n = tid + rep * 512;
    if (n >= Dd) break;
    const uint4* Vrow = (const uint4*)(Vt + ((long)k * Dd + n) * 4096 + b * 512);
    float acc[7] = {};
    for (int m8 = 0; m8 < 64; m8++) {
      uint4 vv = Vrow[m8];
#pragma unroll
      for (int l = 0; l < 7; l++) {
        const unsigned* ap = (const unsigned*)&ash[l][0];
        acc[l] = dot2u(ap[m8 * 4],     vv.x, acc[l]);
        acc[l] = dot2u(ap[m8 * 4 + 1], vv.y, acc[l]);
        acc[l] = dot2u(ap[m8 * 4 + 2], vv.z, acc[l]);
        acc[l] = dot2u(ap[m8 * 4 + 3], vv.w, acc[l]);
      }
    }
#pragma unroll
    for (int l = 0; l < 7; l++)
      outsm[((long)blk * 7 + l) * Dd + n] = __float2bfloat16(acc[l]);
  }
}

// ---------- GRU v4: 1024 thr = (ch:256, q:4); 3 rows/thread = 96 weight VGPRs
// (fits the 128-VGPR budget at 4 waves/SIMD — no AGPR moves on the hot dot2s);
// double-buffered h; DPP quad reduction; 2-deep x global prefetch ----------
__global__ __launch_bounds__(1024, 4) void gru_kernel(
    const bf16* __restrict__ seqW,   // [2][4096][768], includes bih
    const float* __restrict__ PVW,   // [2][768][768]; rows n*7+l and 640+l(emb)
    const void* __restrict__ labels,
    const void* __restrict__ Whh, const void* __restrict__ bhh,
    float* __restrict__ hbuf, const int* __restrict__ flags)
{
  int flag = flags[0], lflag = flags[1];
  int idx = blockIdx.x;
  int dir = idx / 88, n = idx - dir * 88;
  int b = n & 7;
  int tid = threadIdx.x;
  int q = tid & 3, ch = tid >> 2;   // quad owns one channel
  int r0 = ch, r1 = 256 + ch, r2 = 512 + ch;

  // 3 rows × 64-half k-quarter, packed fp16x2 -> 96 VGPRs (hot, arch-resident)
  unsigned w[3][32];
#pragma unroll
  for (int g = 0; g < 3; g++) {
    long base = ((long)dir * Dd + g * 256 + ch) * Hh + q * 64;
    if (flag) {
      const float4* s4 = (const float4*)((const float*)Whh + base);
#pragma unroll
      for (int i = 0; i < 16; i++) {
        float4 v = s4[i];
        w[g][2 * i]     = packh2(v.x, v.y);
        w[g][2 * i + 1] = packh2(v.z, v.w);
      }
    } else {
      const uint4* s4 = (const uint4*)((const bf16*)Whh + base);
#pragma unroll
      for (int i = 0; i < 8; i++) {
        uint4 v = s4[i];
        w[g][4 * i]     = packh2(blo(v.x), bhi(v.x));
        w[g][4 * i + 1] = packh2(blo(v.y), bhi(v.y));
        w[g][4 * i + 2] = packh2(blo(v.z), bhi(v.z));
        w[g][4 * i + 3] = packh2(blo(v.w), bhi(v.w));
      }
    }
  }
  float bh0 = ldg_any(bhh, dir * Dd + r0, flag);
  float bh1 = ldg_any(bhh, dir * Dd + r1, flag);
  float bh2 = ldg_any(bhh, dir * Dd + r2, flag);

  __shared__ float rowsh[7 * 768];
  __shared__ int labsh[512];
  __shared__ __align__(16) unsigned short hsh[2][288];  // dbuf, padded quarters (72)

  for (int i = tid; i < 7 * 768; i += 1024) {
    int l = i / 768, row = i - l * 768;
    rowsh[i] = PVW[((long)dir * 768 + n * 7 + l) * Dd + row]
             + PVW[((long)dir * 768 + 640 + l) * Dd + row];
  }
  if (tid < 512)
    labsh[tid] = lflag ? (int)((const long long*)labels)[b * 512 + tid]
                       : ((const int*)labels)[b * 512 + tid];
  if (tid < 288) { hsh[0][tid] = 0; hsh[1][tid] = 0; }
  __syncthreads();

  const unsigned short* swu = (const unsigned short*)seqW
                            + ((long)dir * 4096 + b * 512) * Dd;
  // 2-deep x pipeline
  int t0 = dir ? 511 : 0, t1 = dir ? 510 : 1;
  unsigned short xs00 = swu[(long)t0 * Dd + r0];
  unsigned short xs01 = swu[(long)t0 * Dd + r1];
  unsigned short xs02 = swu[(long)t0 * Dd + r2];
  unsigned short xs10 = swu[(long)t1 * Dd + r0];
  unsigned short xs11 = swu[(long)t1 * Dd + r1];
  unsigned short xs12 = swu[(long)t1 * Dd + r2];

  float hprev = 0.f;
  int hwaddr = (ch >> 6) * 72 + (ch & 63);
  for (int tt = 0; tt < Ss; tt++) {
    int t = dir ? 511 - tt : tt;
    int ttp = (tt + 2 < Ss) ? tt + 2 : Ss - 1;
    int tp = dir ? 511 - ttp : ttp;
    // prefetch x for tt+2 — lds_barrier leaves these in flight
    unsigned short xp0 = swu[(long)tp * Dd + r0];
    unsigned short xp1 = swu[(long)tp * Dd + r1];
    unsigned short xp2 = swu[(long)tp * Dd + r2];
    // gate inputs (independent of this step's h)
    int lab = labsh[t];
    const float* rs = rowsh + lab * 768;
    float xr = rs[r0] + b2f(xs00);
    float xz = rs[r1] + b2f(xs01);
    float xn = rs[r2] + b2f(xs02);
    // h matvec: this thread's k-quarter of all 3 gates for channel ch
    const uint4* hq = (const uint4*)(hsh[tt & 1] + q * 72);
    float a0 = 0.f, a1 = 0.f, a2 = 0.f;
#pragma unroll
    for (int jj = 0; jj < 8; jj++) {
      uint4 hv = hq[jj];
      a0 = dot2u(w[0][4 * jj],     hv.x, a0);
      a0 = dot2u(w[0][4 * jj + 1], hv.y, a0);
      a0 = dot2u(w[0][4 * jj + 2], hv.z, a0);
      a0 = dot2u(w[0][4 * jj + 3], hv.w, a0);
      a1 = dot2u(w[1][4 * jj],     hv.x, a1);
      a1 = dot2u(w[1][4 * jj + 1], hv.y, a1);
      a1 = dot2u(w[1][4 * jj + 2], hv.z, a1);
      a1 = dot2u(w[1][4 * jj + 3], hv.w, a1);
      a2 = dot2u(w[2][4 * jj],     hv.x, a2);
      a2 = dot2u(w[2][4 * jj + 1], hv.y, a2);
      a2 = dot2u(w[2][4 * jj + 2], hv.z, a2);
      a2 = dot2u(w[2][4 * jj + 3], hv.w, a2);
    }
    a0 = quad_sum(a0);
    a1 = quad_sum(a1);
    a2 = quad_sum(a2);
    float rg = 1.f / (1.f + __expf(-(xr + a0 + bh0)));
    float zg = 1.f / (1.f + __expf(-(xz + a1 + bh1)));
    float targ = xn + rg * (a2 + bh2);
    float e2 = __expf(2.f * targ);
    float ng = 1.f - 2.f / (e2 + 1.f);
    float hnew = (1.f - zg) * ng + zg * hprev;
    hprev = hnew;
    if (q == 0) hsh[(tt + 1) & 1][hwaddr] = f2h(hnew);
    lds_barrier();
    xs00 = xs10; xs01 = xs11; xs02 = xs12;
    xs10 = xp0;  xs11 = xp1;  xs12 = xp2;
  }
  if (q == 0) hbuf[((long)(dir * 88 + n)) * Hh + ch] = hprev;
}

// ---------- final head ----------
__global__ __launch_bounds__(256) void head_kernel(
    const float* __restrict__ hbuf, const void* __restrict__ W1,
    const void* __restrict__ b1, void* __restrict__ out,
    const int* __restrict__ flags)
{
  int flag = flags[0];
  int n = blockIdx.x;
  int c = threadIdx.x;
  float v = hbuf[(long)n * Hh + c] * ldg_any(W1, c, flag)
          + hbuf[(long)(88 + n) * Hh + c] * ldg_any(W1, 256 + c, flag);
  for (int o = 32; o > 0; o >>= 1) v += __shfl_down(v, o);
  __shared__ float red[4];
  if ((c & 63) == 0) red[c >> 6] = v;
  __syncthreads();
  if (c == 0) {
    float s = red[0] + red[1] + red[2] + red[3] + ldg_any(b1, 0, flag);
    float sig = 1.f / (1.f + __expf(-s));
    int k = n / Bb, b = n - k * Bb;
    int o = b * NATT + k;
    if (flag) ((float*)out)[o] = sig;
    else      stf((bf16*)out + o, sig);
  }
}

extern "C" void kernel_launch(void* const* d_in, const int* in_sizes, int n_in,
                              void* d_out, int out_size, void* d_ws, size_t ws_size,
                              hipStream_t stream) {
  const void* labels = d_in[0];
  const void* seq  = d_in[1];
  const void* emb  = d_in[2];
  const void* Wq   = d_in[3];
  const void* bq   = d_in[4];
  const void* Wk   = d_in[5];
  const void* bk   = d_in[6];
  const void* Wv   = d_in[7];
  const void* bv   = d_in[8];
  const void* Wih  = d_in[9];
  const void* Whh  = d_in[10];
  const void* bih  = d_in[11];
  const void* bhh  = d_in[12];
  const void* W1   = d_in[13];
  const void* b1   = d_in[14];

  char* p = (char*)d_ws;
  size_t off = 0;
  auto alloc = [&](size_t bytes) -> void* {
    void* r = p + off; off += (bytes + 255) & ~(size_t)255; return r;
  };
  int*    flags  = (int*)alloc(2 * sizeof(int));
  bf16*   seqb   = (bf16*)alloc(4096UL * 768 * 2);
  float*  qmask7 = (float*)alloc(7 * 4);
  float*  Qsmall = (float*)alloc(11UL * 7 * 768 * 4);
  bf16*   WihB   = (bf16*)alloc(2UL * WSLICE * 2);
  bf16*   WT     = (bf16*)alloc(22UL * WSLICE * 2);
  unsigned short* Kb = (unsigned short*)alloc(11UL * 4096 * 768 * 2);
  unsigned short* Vt = (unsigned short*)alloc(11UL * 768 * 4096 * 2);
  bf16*   outsm  = (bf16*)alloc(768UL * 768 * 2);   // 616 attn rows + emb @640..646
  float*  PVW    = (float*)alloc(2UL * 768 * 768 * 4);
  bf16*   seqW   = (bf16*)alloc(2UL * 4096 * 768 * 2);
  float*  hbuf   = (float*)alloc(2UL * 88 * 256 * 4);
  if (off > ws_size) return;

  probe_kernel<<<1, 64, 0, stream>>>((const unsigned short*)seq,
                                     (const unsigned*)labels, flags);
  conv_seq_kernel<<<4096, 256, 0, stream>>>(seq, seqb, flags);
  convert_kernel<<<(int)((2 * WSLICE + 255) / 256), 256, 0, stream>>>(
      Wih, WihB, 2L * WSLICE, flags);
  smalls_kernel<<<dim3(12, 11), 256, 0, stream>>>(emb, Wq, bq, Qsmall, flags);
  emb_copy_kernel<<<7, 256, 0, stream>>>(emb, outsm, qmask7, flags);
  transpose2_kernel<<<dim3(24, 24, 22), 256, 0, stream>>>(Wk, Wv, WT, flags);
  proj_kernel<<<dim3(6, 32, 22), 256, 0, stream>>>(
      seqb, WT, bk, bv, Kb, Vt, flags);
  seqw_kernel<<<dim3(6, 32, 2), 256, 0, stream>>>(seqb, WihB, bih, seqW, flags);
  const float scl = 1.f / sqrtf(768.f);
  attn_kernel<<<88, 512, 0, stream>>>(Kb, Vt, Qsmall, qmask7, outsm, scl);
  pvw_kernel<<<dim3(6, 6, 2), 256, 0, stream>>>(outsm, WihB, PVW, flags);
  gru_kernel<<<176, 1024, 0, stream>>>(seqW, PVW, labels, Whh, bhh, hbuf, flags);
  head_kernel<<<88, 256, 0, stream>>>(hbuf, W1, b1, d_out, flags);
}

// Round 11
// 1093.300 us; speedup vs baseline: 1.1351x; 1.1351x over previous
//
#include <hip/hip_runtime.h>
#include <hip/hip_bf16.h>
#include <hip/hip_fp16.h>
#include <math.h>

typedef __hip_bfloat16 bf16;
typedef __attribute__((ext_vector_type(8))) short short8;
typedef __attribute__((ext_vector_type(4))) float f32x4;

#define NATT 11
#define Bb 8
#define Ss 512
#define Dd 768
#define Hh 256
#define WSLICE 589824L  // 768*768

#if defined(__has_attribute)
#if __has_attribute(amdgpu_waves_per_eu)
#define WAVES22 __attribute__((amdgpu_waves_per_eu(2, 2)))
#else
#define WAVES22
#endif
#else
#define WAVES22
#endif

__device__ __forceinline__ void stf(float* p, float v) { *p = v; }
__device__ __forceinline__ void stf(bf16* p, float v) { *p = __float2bfloat16(v); }

__device__ __forceinline__ float blo(unsigned u) { return __uint_as_float(u << 16); }
__device__ __forceinline__ float bhi(unsigned u) { return __uint_as_float(u & 0xffff0000u); }
__device__ __forceinline__ float b2f(unsigned short u) { return __uint_as_float(((unsigned)u) << 16); }

__device__ __forceinline__ float ldg_any(const void* base, long idx, int flag) {
  if (flag) return ((const float*)base)[idx];
  return __bfloat162float(((const bf16*)base)[idx]);
}

__device__ __forceinline__ unsigned packh2(float a, float b) {
  __half2 hh = __floats2half2_rn(a, b);
  return __builtin_bit_cast(unsigned, hh);
}
__device__ __forceinline__ unsigned short f2h(float v) {
  __half h = __float2half(v);
  return __builtin_bit_cast(unsigned short, h);
}

typedef _Float16 f16x2 __attribute__((ext_vector_type(2)));

__device__ __forceinline__ float dot2u(unsigned a, unsigned b, float c) {
#if __has_builtin(__builtin_amdgcn_fdot2)
  return __builtin_amdgcn_fdot2(__builtin_bit_cast(f16x2, a),
                                __builtin_bit_cast(f16x2, b), c, false);
#else
  __half2 ah = __builtin_bit_cast(__half2, a);
  __half2 bh = __builtin_bit_cast(__half2, b);
  float2 af = __half22float2(ah), bf = __half22float2(bh);
  return c + af.x * bf.x + af.y * bf.y;
#endif
}

// sum across a lane-quad using DPP quad_perm (VALU only, no LDS)
__device__ __forceinline__ float quad_sum(float v) {
#if __has_builtin(__builtin_amdgcn_update_dpp)
  int y = __builtin_amdgcn_update_dpp(0, __builtin_bit_cast(int, v), 0xB1, 0xF, 0xF, true);
  v += __builtin_bit_cast(float, y);
  y = __builtin_amdgcn_update_dpp(0, __builtin_bit_cast(int, v), 0x4E, 0xF, 0xF, true);
  v += __builtin_bit_cast(float, y);
  return v;
#else
  v += __shfl_xor(v, 1);
  v += __shfl_xor(v, 2);
  return v;
#endif
}

// barrier that drains ONLY LDS (lgkmcnt) — leaves global prefetches in flight.
__device__ __forceinline__ void lds_barrier() {
  asm volatile("s_waitcnt lgkmcnt(0)\n\ts_barrier" ::: "memory");
}

__device__ __forceinline__ void load_lds16(const void* g, void* l) {
  __builtin_amdgcn_global_load_lds(
      (const __attribute__((address_space(1))) unsigned int*)g,
      (__attribute__((address_space(3))) unsigned int*)l, 16, 0, 0);
}

// ---------- dtype probe ----------
__global__ __launch_bounds__(64) void probe_kernel(
    const unsigned short* __restrict__ sequ, const unsigned* __restrict__ labu,
    int* __restrict__ flags)
{
  int t = threadIdx.x;
  int wild = 0;
#pragma unroll
  for (int i = 0; i < 4; i++) {
    unsigned short v = sequ[t + i * 64];
    int e = (v >> 7) & 0xFF;
    if (e < 90 || e > 160) wild++;
  }
  int nzodd = 0;
#pragma unroll
  for (int i = 0; i < 2; i++) {
    unsigned w = labu[(t + i * 64) * 2 + 1];
    if (w != 0) nzodd++;
  }
  for (int o = 32; o > 0; o >>= 1) {
    wild  += __shfl_down(wild, o);
    nzodd += __shfl_down(nzodd, o);
  }
  if (t == 0) {
    flags[0] = (wild > 32) ? 1 : 0;
    flags[1] = (nzodd == 0) ? 1 : 0;
  }
}

// ---------- seq -> bf16 ----------
__global__ __launch_bounds__(256) void conv_seq_kernel(
    const void* __restrict__ seq, bf16* __restrict__ seqb,
    const int* __restrict__ flags)
{
  int flag = flags[0];
  long row = blockIdx.x;
#pragma unroll
  for (int i = 0; i < 3; i++) {
    long e = row * Dd + threadIdx.x + i * 256;
    seqb[e] = __float2bfloat16(ldg_any(seq, e, flag));
  }
}

// ---------- generic convert to bf16 (Wih) ----------
__global__ __launch_bounds__(256) void convert_kernel(
    const void* __restrict__ src, bf16* __restrict__ dst, long n,
    const int* __restrict__ flags)
{
  int flag = flags[0];
  long i = (long)blockIdx.x * 256 + threadIdx.x;
  if (i < n) dst[i] = __float2bfloat16(ldg_any(src, i, flag));
}

// ---------- Qsmall[11][7][768] = relu(emb7 @ Wq + bq); grid (12, 11) ----------
__global__ __launch_bounds__(256) void smalls_kernel(
    const void* __restrict__ emb, const void* __restrict__ Wq,
    const void* __restrict__ bq, float* __restrict__ Qsmall,
    const int* __restrict__ flags)
{
  int flag = flags[0];
  __shared__ float embsh[7 * 768];
  __shared__ float psum[4][7][64];
  int z = blockIdx.y;
  int bx = blockIdx.x;
  int tid = threadIdx.x;
  int sub = tid >> 6, nl = tid & 63;
  for (int i = tid; i < 7 * 768; i += 256) embsh[i] = ldg_any(emb, i, flag);
  __syncthreads();
  int n = bx * 64 + nl;
  long base = (long)z * WSLICE;
  float acc[7] = {};
  int e0 = sub * 192;
  for (int e = e0; e < e0 + 192; e++) {
    float wv = ldg_any(Wq, base + (long)e * Dd + n, flag);
#pragma unroll
    for (int l = 0; l < 7; l++) acc[l] += embsh[l * 768 + e] * wv;
  }
#pragma unroll
  for (int l = 0; l < 7; l++) psum[sub][l][nl] = acc[l];
  __syncthreads();
  if (sub == 0) {
    float bv = ldg_any(bq, z * Dd + n, flag);
#pragma unroll
    for (int l = 0; l < 7; l++) {
      float v = psum[0][l][nl] + psum[1][l][nl] + psum[2][l][nl] + psum[3][l][nl] + bv;
      Qsmall[((long)z * 7 + l) * Dd + n] = fmaxf(v, 0.f);
    }
  }
}

// ---------- emb rows -> outsm[640+l] (bf16) + qmask7 ----------
__global__ __launch_bounds__(256) void emb_copy_kernel(
    const void* __restrict__ emb, bf16* __restrict__ outsm,
    float* __restrict__ qmask7, const int* __restrict__ flags)
{
  int flag = flags[0];
  int l = blockIdx.x;
  int t = threadIdx.x;
  float s = 0.f;
#pragma unroll
  for (int i = 0; i < 3; i++) {
    int e = t + i * 256;
    float v = ldg_any(emb, (long)l * Dd + e, flag);
    outsm[(long)(640 + l) * Dd + e] = __float2bfloat16(v);
    s += v;
  }
  for (int o = 32; o > 0; o >>= 1) s += __shfl_down(s, o);
  __shared__ float red[4];
  if ((t & 63) == 0) red[t >> 6] = s;
  __syncthreads();
  if (t == 0) {
    float tot = red[0] + red[1] + red[2] + red[3];
    qmask7[l] = (tot != 0.f) ? 1.f : 0.f;
  }
}

// ---------- transpose Wk/Wv branch slices to [N][K] bf16 ----------
__global__ __launch_bounds__(256) void transpose2_kernel(
    const void* __restrict__ Wk, const void* __restrict__ Wv,
    bf16* __restrict__ WT, const int* __restrict__ flags)
{
  int flag = flags[0];
  __shared__ float tile[32][33];
  int z = blockIdx.z;
  int m = z >> 1, wsel = z & 1;
  const void* src = wsel ? Wv : Wk;
  long off = (long)m * WSLICE;
  bf16* dst = WT + (long)z * WSLICE;
  int kk0 = blockIdx.y * 32, n0 = blockIdx.x * 32;
  int tx = threadIdx.x & 31, ty = threadIdx.x >> 5;
#pragma unroll
  for (int i = 0; i < 4; i++)
    tile[ty + i * 8][tx] = ldg_any(src, off + (long)(kk0 + ty + i * 8) * Dd + n0 + tx, flag);
  __syncthreads();
#pragma unroll
  for (int i = 0; i < 4; i++)
    dst[(long)(n0 + ty + i * 8) * Dd + kk0 + tx] = __float2bfloat16(tile[tx][ty + i * 8]);
}

// ---------- MFMA GEMM core: C = epi(scale*A@B^T) ----------
// cMode: 0=bf16, 2=fp32, 3=fp16, 5=fp16 transposed via LDS bounce (coalesced).
// cMode 5 REQUIRES As,Bs to be one contiguous 16KB block (As base used as a
// [32][136] ushort bounce tile = 8704B, spilling into the Bs region).
__device__ __forceinline__ void gemm_mfma_core(
    const bf16* __restrict__ Ab, long ldA,
    const bf16* __restrict__ Bbp, long ldB,
    bf16* As, bf16* Bs, int bm, int bn, int K,
    const void* bias, long bOff,
    void* C, long ldC, int cMode,
    float scale, int relu, int fflag)
{
  int tid = threadIdx.x;
  int lane = tid & 63, w = tid >> 6;
  int mo = (w & 1) * 64, no = (w >> 1) * 64;
  int l15 = lane & 15, q4 = lane >> 4;
  int gr = lane >> 2;
  int gs = (lane & 3) * 8;
  const bf16* aS0 = Ab + (long)(bm + w * 16 + gr) * ldA + gs;
  const bf16* aS1 = aS0 + 64 * ldA;
  const bf16* bS0 = Bbp + (long)(bn + w * 16 + gr) * ldB + gs;
  const bf16* bS1 = bS0 + 64 * ldB;
  bf16* aD0 = As + w * 512;
  bf16* aD1 = As + 2048 + w * 512;
  bf16* bD0 = Bs + w * 512;
  bf16* bD1 = Bs + 2048 + w * 512;

  f32x4 acc[4][4];
#pragma unroll
  for (int i = 0; i < 4; i++)
#pragma unroll
    for (int j = 0; j < 4; j++)
#pragma unroll
      for (int r = 0; r < 4; r++) acc[i][j][r] = 0.f;

  for (int k0 = 0; k0 < K; k0 += 32) {
    load_lds16(aS0, aD0);
    load_lds16(aS1, aD1);
    load_lds16(bS0, bD0);
    load_lds16(bS1, bD1);
    aS0 += 32; aS1 += 32; bS0 += 32; bS1 += 32;
    __syncthreads();
    short8 af[4], bfv[4];
#pragma unroll
    for (int i = 0; i < 4; i++)
      af[i] = *(const short8*)(As + (mo + i * 16 + l15) * 32 + q4 * 8);
#pragma unroll
    for (int j = 0; j < 4; j++)
      bfv[j] = *(const short8*)(Bs + (no + j * 16 + l15) * 32 + q4 * 8);
#pragma unroll
    for (int i = 0; i < 4; i++)
#pragma unroll
      for (int j = 0; j < 4; j++)
        acc[i][j] = __builtin_amdgcn_mfma_f32_16x16x32_bf16(af[i], bfv[j], acc[i][j], 0, 0, 0);
    __syncthreads();
  }

  float bsv[4];
#pragma unroll
  for (int j = 0; j < 4; j++) {
    int colg = bn + no + j * 16 + l15;
    bsv[j] = bias ? ldg_any(bias, bOff + colg, fflag) : 0.f;
  }

  if (cMode == 5) {
    // transposed fp16 store, LDS-bounced for coalescing.
    unsigned short* tile = (unsigned short*)As;   // [32][136]
    int cl = (no >> 6) * 16 + l15;                // local col 0..31
#pragma unroll
    for (int j = 0; j < 4; j++) {
      __syncthreads();
#pragma unroll
      for (int i = 0; i < 4; i++) {
#pragma unroll
        for (int r = 0; r < 4; r++) {
          float v = acc[i][j][r] * scale + bsv[j];
          if (relu) v = fmaxf(v, 0.f);
          tile[cl * 136 + mo + i * 16 + q4 * 4 + r] = f2h(v);
        }
      }
      __syncthreads();
      // 32 cols x 16 msegs(8 m each) = 512 units over 256 threads
#pragma unroll
      for (int uu = 0; uu < 2; uu++) {
        int u = tid + uu * 256;
        int c = u >> 4, mseg = u & 15;
        int colg = bn + (c >> 4) * 64 + j * 16 + (c & 15);
        uint2 v0 = *(const uint2*)(tile + c * 136 + mseg * 8);
        uint2 v1 = *(const uint2*)(tile + c * 136 + mseg * 8 + 4);
        uint4 pk; pk.x = v0.x; pk.y = v0.y; pk.z = v1.x; pk.w = v1.y;
        *(uint4*)((unsigned short*)C + (long)colg * ldC + bm + mseg * 8) = pk;
      }
    }
    return;
  }

#pragma unroll
  for (int i = 0; i < 4; i++) {
#pragma unroll
    for (int j = 0; j < 4; j++) {
      int colg = bn + no + j * 16 + l15;
#pragma unroll
      for (int r = 0; r < 4; r++) {
        int rowg = bm + mo + i * 16 + q4 * 4 + r;
        float v = acc[i][j][r] * scale + bsv[j];
        if (relu) v = fmaxf(v, 0.f);
        long off2 = (long)rowg * ldC + colg;
        if (cMode == 2)      ((float*)C)[off2] = v;
        else if (cMode == 3) ((unsigned short*)C)[off2] = f2h(v);
        else                 ((bf16*)C)[off2] = __float2bfloat16(v);
      }
    }
  }
}

// ---------- K/V projections (fp16 out), z = m*2 + {0:K,1:V} ----------
__global__ __launch_bounds__(256, 2) void proj_kernel(
    const bf16* __restrict__ seqb, const bf16* __restrict__ WT,
    const void* __restrict__ bk, const void* __restrict__ bv,
    unsigned short* __restrict__ Kb, unsigned short* __restrict__ Vt,
    const int* __restrict__ flags)
{
  __shared__ __align__(16) bf16 smem[8192];   // contiguous As+Bs (cMode 5 needs this)
  bf16* As = smem;
  bf16* Bs = smem + 4096;
  int z = blockIdx.z;
  int m = z >> 1, wsel = z & 1;
  const bf16* B = WT + (long)z * WSLICE;
  if (wsel == 0) {
    gemm_mfma_core(seqb, Dd, B, Dd, As, Bs, blockIdx.y * 128, blockIdx.x * 128, Dd,
                   bk, (long)m * Dd, Kb + (long)m * 4096 * Dd, Dd, 3, 1.f, 1, flags[0]);
  } else {
    gemm_mfma_core(seqb, Dd, B, Dd, As, Bs, blockIdx.y * 128, blockIdx.x * 128, Dd,
                   bv, (long)m * Dd, Vt + (long)m * Dd * 4096, 4096, 5, 1.f, 1, flags[0]);
  }
}

// ---------- seqW = seq @ Wih^T + bih (bf16), z = dir ----------
__global__ __launch_bounds__(256, 2) void seqw_kernel(
    const bf16* __restrict__ seqb, const bf16* __restrict__ WihB,
    const void* __restrict__ bih, bf16* __restrict__ seqW,
    const int* __restrict__ flags)
{
  __shared__ __align__(16) bf16 As[4096];
  __shared__ __align__(16) bf16 Bs[4096];
  int dir = blockIdx.z;
  gemm_mfma_core(seqb, Dd, WihB + (long)dir * WSLICE, Dd, As, Bs,
                 blockIdx.y * 128, blockIdx.x * 128, Dd,
                 bih, (long)dir * Dd, seqW + (long)dir * 4096 * Dd, Dd, 0,
                 1.f, 0, flags[0]);
}

// ---------- PVW = outsm(768 rows incl emb @640) @ Wih^T (fp32), z = dir ----------
__global__ __launch_bounds__(256, 2) void pvw_kernel(
    const bf16* __restrict__ outsm, const bf16* __restrict__ WihB,
    float* __restrict__ PVW, const int* __restrict__ flags)
{
  __shared__ __align__(16) bf16 As[4096];
  __shared__ __align__(16) bf16 Bs[4096];
  int dir = blockIdx.z;
  gemm_mfma_core(outsm, Dd, WihB + (long)dir * WSLICE, Dd, As, Bs,
                 blockIdx.y * 128, blockIdx.x * 128, Dd,
                 nullptr, 0, PVW + (long)dir * 768 * Dd, Dd, 2, 1.f, 0, flags[0]);
}

// ---------- fused scores+softmax+mask+PV per (k,b) ----------
__global__ __launch_bounds__(512, 2) void attn_kernel(
    const unsigned short* __restrict__ Kb, const unsigned short* __restrict__ Vt,
    const float* __restrict__ Qsmall, const float* __restrict__ qmask7,
    bf16* __restrict__ outsm, float scl)
{
  int blk = blockIdx.x;  // k*8+b
  int k = blk >> 3, b = blk & 7;
  int tid = threadIdx.x;
  int lane = tid & 63, w = tid >> 6;
  __shared__ unsigned qs[7][384];
  __shared__ unsigned short ash[7][512];
  __shared__ float wred[8][7];
  __shared__ float gred[7];
  __shared__ float finv[7];
  for (int i = tid; i < 7 * 384; i += 512) {
    int l = i / 384, e2 = i - l * 384;
    const float* qp = Qsmall + ((long)k * 7 + l) * Dd + 2 * e2;
    qs[l][e2] = packh2(qp[0], qp[1]);
  }
  __syncthreads();
  const uint4* Krow = (const uint4*)(Kb + ((long)k * 4096 + b * 512 + tid) * Dd);
  float sc[7] = {};
  for (int e8 = 0; e8 < 96; e8++) {
    uint4 kv = Krow[e8];
#pragma unroll
    for (int l = 0; l < 7; l++) {
      sc[l] = dot2u(qs[l][e8 * 4],     kv.x, sc[l]);
      sc[l] = dot2u(qs[l][e8 * 4 + 1], kv.y, sc[l]);
      sc[l] = dot2u(qs[l][e8 * 4 + 2], kv.z, sc[l]);
      sc[l] = dot2u(qs[l][e8 * 4 + 3], kv.w, sc[l]);
    }
  }
#pragma unroll
  for (int l = 0; l < 7; l++) sc[l] *= scl;
#pragma unroll
  for (int l = 0; l < 7; l++) {
    float v = sc[l];
    for (int o = 32; o > 0; o >>= 1) v = fmaxf(v, __shfl_down(v, o));
    if (lane == 0) wred[w][l] = v;
  }
  __syncthreads();
  if (tid < 7) {
    float m = wred[0][tid];
#pragma unroll
    for (int i = 1; i < 8; i++) m = fmaxf(m, wred[i][tid]);
    gred[tid] = m;
  }
  __syncthreads();
  float ev[7];
#pragma unroll
  for (int l = 0; l < 7; l++) {
    ev[l] = __expf(sc[l] - gred[l]);
    float v = ev[l];
    for (int o = 32; o > 0; o >>= 1) v += __shfl_down(v, o);
    if (lane == 0) wred[w][l] = v;
  }
  __syncthreads();
  if (tid < 7) {
    float s = 0.f;
#pragma unroll
    for (int i = 0; i < 8; i++) s += wred[i][tid];
    finv[tid] = qmask7[tid] / s;
  }
  __syncthreads();
#pragma unroll
  for (int l = 0; l < 7; l++) ash[l][tid] = f2h(ev[l] * finv[l]);
  __syncthreads();
  for (int rep = 0; rep < 2; rep++) {
    int n = tid + rep * 512;
    if (n >= Dd) break;
    const uint4* Vrow = (const uint4*)(Vt + ((long)k * Dd + n) * 4096 + b * 512);
    float acc[7] = {};
    for (int m8 = 0; m8 < 64; m8++) {
      uint4 vv = Vrow[m8];
#pragma unroll
      for (int l = 0; l < 7; l++) {
        const unsigned* ap = (const unsigned*)&ash[l][0];
        acc[l] = dot2u(ap[m8 * 4],     vv.x, acc[l]);
        acc[l] = dot2u(ap[m8 * 4 + 1], vv.y, acc[l]);
        acc[l] = dot2u(ap[m8 * 4 + 2], vv.z, acc[l]);
        acc[l] = dot2u(ap[m8 * 4 + 3], vv.w, acc[l]);
      }
    }
#pragma unroll
    for (int l = 0; l < 7; l++)
      outsm[((long)blk * 7 + l) * Dd + n] = __float2bfloat16(acc[l]);
  }
}

// ---------- GRU v5: R9 structure + waves_per_eu(2,2) so the 192 weight regs
// stay in arch VGPRs (grid 176 < 256 CUs — occupancy is grid-limited anyway,
// so capping at 2 waves/EU costs nothing and kills the AGPR-move tax) ----------
__global__ __launch_bounds__(512) WAVES22 void gru_kernel(
    const bf16* __restrict__ seqW,   // [2][4096][768], includes bih
    const float* __restrict__ PVW,   // [2][768][768]; rows n*7+l and 640+l(emb)
    const void* __restrict__ labels,
    const void* __restrict__ Whh, const void* __restrict__ bhh,
    float* __restrict__ hbuf, const int* __restrict__ flags)
{
  int flag = flags[0], lflag = flags[1];
  int idx = blockIdx.x;
  int dir = idx / 88, n = idx - dir * 88;
  int b = n & 7;
  int tid = threadIdx.x;
  int q = tid & 3, cg = tid >> 2;
  int hi = q >> 1;
  int ch = cg + hi * 128;
  int r0 = ch, r1 = 256 + ch, r2 = 512 + ch;

  // 6 rows × 64-half k-quarter, packed fp16x2 -> 192 VGPRs
  unsigned w[6][32];
#pragma unroll
  for (int s = 0; s < 6; s++) {
    int row = (s >> 1) * 256 + cg + (s & 1) * 128;
    long base = ((long)dir * Dd + row) * Hh + q * 64;
    if (flag) {
      const float4* s4 = (const float4*)((const float*)Whh + base);
#pragma unroll
      for (int i = 0; i < 16; i++) {
        float4 v = s4[i];
        w[s][2 * i]     = packh2(v.x, v.y);
        w[s][2 * i + 1] = packh2(v.z, v.w);
      }
    } else {
      const uint4* s4 = (const uint4*)((const bf16*)Whh + base);
#pragma unroll
      for (int i = 0; i < 8; i++) {
        uint4 v = s4[i];
        w[s][4 * i]     = packh2(blo(v.x), bhi(v.x));
        w[s][4 * i + 1] = packh2(blo(v.y), bhi(v.y));
        w[s][4 * i + 2] = packh2(blo(v.z), bhi(v.z));
        w[s][4 * i + 3] = packh2(blo(v.w), bhi(v.w));
      }
    }
  }
  float bh0 = ldg_any(bhh, dir * Dd + r0, flag);
  float bh1 = ldg_any(bhh, dir * Dd + r1, flag);
  float bh2 = ldg_any(bhh, dir * Dd + r2, flag);

  __shared__ float rowsh[7 * 768];
  __shared__ int labsh[512];
  __shared__ __align__(16) unsigned short hsh[2][4 * 72];

  for (int i = tid; i < 7 * 768; i += 512) {
    int l = i / 768, row = i - l * 768;
    rowsh[i] = PVW[((long)dir * 768 + n * 7 + l) * Dd + row]
             + PVW[((long)dir * 768 + 640 + l) * Dd + row];
  }
  labsh[tid] = lflag ? (int)((const long long*)labels)[b * 512 + tid]
                     : ((const int*)labels)[b * 512 + tid];
  if (tid < 288) { hsh[0][tid] = 0; hsh[1][tid] = 0; }
  __syncthreads();

  const unsigned short* swu = (const unsigned short*)seqW
                            + ((long)dir * 4096 + b * 512) * Dd;
  int t0 = dir ? 511 : 0, t1 = dir ? 510 : 1, t2 = dir ? 509 : 2;
  unsigned short xs00 = swu[(long)t0 * Dd + r0];
  unsigned short xs01 = swu[(long)t0 * Dd + r1];
  unsigned short xs02 = swu[(long)t0 * Dd + r2];
  unsigned short xs10 = swu[(long)t1 * Dd + r0];
  unsigned short xs11 = swu[(long)t1 * Dd + r1];
  unsigned short xs12 = swu[(long)t1 * Dd + r2];
  unsigned short xs20 = swu[(long)t2 * Dd + r0];
  unsigned short xs21 = swu[(long)t2 * Dd + r1];
  unsigned short xs22 = swu[(long)t2 * Dd + r2];

  float hprev = 0.f;
  int hwaddr = (ch >> 6) * 72 + (ch & 63);
  for (int tt = 0; tt < Ss; tt++) {
    int t = dir ? 511 - tt : tt;
    int ttp = (tt + 3 < Ss) ? tt + 3 : Ss - 1;
    int tp = dir ? 511 - ttp : ttp;
    unsigned short xp0 = swu[(long)tp * Dd + r0];
    unsigned short xp1 = swu[(long)tp * Dd + r1];
    unsigned short xp2 = swu[(long)tp * Dd + r2];
    int lab = labsh[t];
    const float* rs = rowsh + lab * 768;
    float xr = rs[r0] + b2f(xs00);
    float xz = rs[r1] + b2f(xs01);
    float xn = rs[r2] + b2f(xs02);
    const uint4* hq = (const uint4*)(hsh[tt & 1] + q * 72);
    float a[6] = {};
#pragma unroll
    for (int jj = 0; jj < 8; jj++) {
      uint4 hv = hq[jj];
#pragma unroll
      for (int s = 0; s < 6; s++) {
        a[s] = dot2u(w[s][4 * jj],     hv.x, a[s]);
        a[s] = dot2u(w[s][4 * jj + 1], hv.y, a[s]);
        a[s] = dot2u(w[s][4 * jj + 2], hv.z, a[s]);
        a[s] = dot2u(w[s][4 * jj + 3], hv.w, a[s]);
      }
    }
#pragma unroll
    for (int s = 0; s < 6; s++) a[s] = quad_sum(a[s]);
    float ar = hi ? a[1] : a[0];
    float az = hi ? a[3] : a[2];
    float an = hi ? a[5] : a[4];
    float rg = 1.f / (1.f + __expf(-(xr + ar + bh0)));
    float zg = 1.f / (1.f + __expf(-(xz + az + bh1)));
    float targ = xn + rg * (an + bh2);
    float e2 = __expf(2.f * targ);
    float ng = 1.f - 2.f / (e2 + 1.f);
    float hnew = (1.f - zg) * ng + zg * hprev;
    hprev = hnew;
    if ((q & 1) == 0) hsh[(tt + 1) & 1][hwaddr] = f2h(hnew);
    lds_barrier();
    xs00 = xs10; xs01 = xs11; xs02 = xs12;
    xs10 = xs20; xs11 = xs21; xs12 = xs22;
    xs20 = xp0;  xs21 = xp1;  xs22 = xp2;
  }
  if ((q & 1) == 0) hbuf[((long)(dir * 88 + n)) * Hh + ch] = hprev;
}

// ---------- final head ----------
__global__ __launch_bounds__(256) void head_kernel(
    const float* __restrict__ hbuf, const void* __restrict__ W1,
    const void* __restrict__ b1, void* __restrict__ out,
    const int* __restrict__ flags)
{
  int flag = flags[0];
  int n = blockIdx.x;
  int c = threadIdx.x;
  float v = hbuf[(long)n * Hh + c] * ldg_any(W1, c, flag)
          + hbuf[(long)(88 + n) * Hh + c] * ldg_any(W1, 256 + c, flag);
  for (int o = 32; o > 0; o >>= 1) v += __shfl_down(v, o);
  __shared__ float red[4];
  if ((c & 63) == 0) red[c >> 6] = v;
  __syncthreads();
  if (c == 0) {
    float s = red[0] + red[1] + red[2] + red[3] + ldg_any(b1, 0, flag);
    float sig = 1.f / (1.f + __expf(-s));
    int k = n / Bb, b = n - k * Bb;
    int o = b * NATT + k;
    if (flag) ((float*)out)[o] = sig;
    else      stf((bf16*)out + o, sig);
  }
}

extern "C" void kernel_launch(void* const* d_in, const int* in_sizes, int n_in,
                              void* d_out, int out_size, void* d_ws, size_t ws_size,
                              hipStream_t stream) {
  const void* labels = d_in[0];
  const void* seq  = d_in[1];
  const void* emb  = d_in[2];
  const void* Wq   = d_in[3];
  const void* bq   = d_in[4];
  const void* Wk   = d_in[5];
  const void* bk   = d_in[6];
  const void* Wv   = d_in[7];
  const void* bv   = d_in[8];
  const void* Wih  = d_in[9];
  const void* Whh  = d_in[10];
  const void* bih  = d_in[11];
  const void* bhh  = d_in[12];
  const void* W1   = d_in[13];
  const void* b1   = d_in[14];

  char* p = (char*)d_ws;
  size_t off = 0;
  auto alloc = [&](size_t bytes) -> void* {
    void* r = p + off; off += (bytes + 255) & ~(size_t)255; return r;
  };
  int*    flags  = (int*)alloc(2 * sizeof(int));
  bf16*   seqb   = (bf16*)alloc(4096UL * 768 * 2);
  float*  qmask7 = (float*)alloc(7 * 4);
  float*  Qsmall = (float*)alloc(11UL * 7 * 768 * 4);
  bf16*   WihB   = (bf16*)alloc(2UL * WSLICE * 2);
  bf16*   WT     = (bf16*)alloc(22UL * WSLICE * 2);
  unsigned short* Kb = (unsigned short*)alloc(11UL * 4096 * 768 * 2);
  unsigned short* Vt = (unsigned short*)alloc(11UL * 768 * 4096 * 2);
  bf16*   outsm  = (bf16*)alloc(768UL * 768 * 2);
  float*  PVW    = (float*)alloc(2UL * 768 * 768 * 4);
  bf16*   seqW   = (bf16*)alloc(2UL * 4096 * 768 * 2);
  float*  hbuf   = (float*)alloc(2UL * 88 * 256 * 4);
  if (off > ws_size) return;

  probe_kernel<<<1, 64, 0, stream>>>((const unsigned short*)seq,
                                     (const unsigned*)labels, flags);
  conv_seq_kernel<<<4096, 256, 0, stream>>>(seq, seqb, flags);
  convert_kernel<<<(int)((2 * WSLICE + 255) / 256), 256, 0, stream>>>(
      Wih, WihB, 2L * WSLICE, flags);
  smalls_kernel<<<dim3(12, 11), 256, 0, stream>>>(emb, Wq, bq, Qsmall, flags);
  emb_copy_kernel<<<7, 256, 0, stream>>>(emb, outsm, qmask7, flags);
  transpose2_kernel<<<dim3(24, 24, 22), 256, 0, stream>>>(Wk, Wv, WT, flags);
  proj_kernel<<<dim3(6, 32, 22), 256, 0, stream>>>(
      seqb, WT, bk, bv, Kb, Vt, flags);
  seqw_kernel<<<dim3(6, 32, 2), 256, 0, stream>>>(seqb, WihB, bih, seqW, flags);
  const float scl = 1.f / sqrtf(768.f);
  attn_kernel<<<88, 512, 0, stream>>>(Kb, Vt, Qsmall, qmask7, outsm, scl);
  pvw_kernel<<<dim3(6, 6, 2), 256, 0, stream>>>(outsm, WihB, PVW, flags);
  gru_kernel<<<176, 512, 0, stream>>>(seqW, PVW, labels, Whh, bhh, hbuf, flags);
  head_kernel<<<88, 256, 0, stream>>>(hbuf, W1, b1, d_out, flags);
}

// Round 13
// 1080.478 us; speedup vs baseline: 1.1486x; 1.0119x over previous
//
#include <hip/hip_runtime.h>
#include <hip/hip_bf16.h>
#include <hip/hip_fp16.h>
#include <math.h>

typedef __hip_bfloat16 bf16;
typedef __attribute__((ext_vector_type(8))) short short8;
typedef __attribute__((ext_vector_type(4))) float f32x4;

#define NATT 11
#define Bb 8
#define Ss 512
#define Dd 768
#define Hh 256
#define WSLICE 589824L  // 768*768

#if defined(__has_attribute)
#if __has_attribute(amdgpu_waves_per_eu)
#define WAVES22 __attribute__((amdgpu_waves_per_eu(2, 2)))
#else
#define WAVES22
#endif
#if __has_attribute(amdgpu_agpr_alloc)
#define NO_AGPR __attribute__((amdgpu_agpr_alloc(0)))
#else
#define NO_AGPR
#endif
#else
#define WAVES22
#define NO_AGPR
#endif

__device__ __forceinline__ void stf(float* p, float v) { *p = v; }
__device__ __forceinline__ void stf(bf16* p, float v) { *p = __float2bfloat16(v); }

__device__ __forceinline__ float blo(unsigned u) { return __uint_as_float(u << 16); }
__device__ __forceinline__ float bhi(unsigned u) { return __uint_as_float(u & 0xffff0000u); }
__device__ __forceinline__ float b2f(unsigned short u) { return __uint_as_float(((unsigned)u) << 16); }

__device__ __forceinline__ float ldg_any(const void* base, long idx, int flag) {
  if (flag) return ((const float*)base)[idx];
  return __bfloat162float(((const bf16*)base)[idx]);
}

__device__ __forceinline__ unsigned packh2(float a, float b) {
  __half2 hh = __floats2half2_rn(a, b);
  return __builtin_bit_cast(unsigned, hh);
}
__device__ __forceinline__ unsigned short f2h(float v) {
  __half h = __float2half(v);
  return __builtin_bit_cast(unsigned short, h);
}

typedef _Float16 f16x2 __attribute__((ext_vector_type(2)));

__device__ __forceinline__ float dot2u(unsigned a, unsigned b, float c) {
#if __has_builtin(__builtin_amdgcn_fdot2)
  return __builtin_amdgcn_fdot2(__builtin_bit_cast(f16x2, a),
                                __builtin_bit_cast(f16x2, b), c, false);
#else
  __half2 ah = __builtin_bit_cast(__half2, a);
  __half2 bh = __builtin_bit_cast(__half2, b);
  float2 af = __half22float2(ah), bf = __half22float2(bh);
  return c + af.x * bf.x + af.y * bf.y;
#endif
}

// sum across a lane-quad using DPP quad_perm (VALU only, no LDS)
__device__ __forceinline__ float quad_sum(float v) {
#if __has_builtin(__builtin_amdgcn_update_dpp)
  int y = __builtin_amdgcn_update_dpp(0, __builtin_bit_cast(int, v), 0xB1, 0xF, 0xF, true);
  v += __builtin_bit_cast(float, y);
  y = __builtin_amdgcn_update_dpp(0, __builtin_bit_cast(int, v), 0x4E, 0xF, 0xF, true);
  v += __builtin_bit_cast(float, y);
  return v;
#else
  v += __shfl_xor(v, 1);
  v += __shfl_xor(v, 2);
  return v;
#endif
}

// barrier that drains ONLY LDS (lgkmcnt) — leaves global prefetches in flight.
__device__ __forceinline__ void lds_barrier() {
  asm volatile("s_waitcnt lgkmcnt(0)\n\ts_barrier" ::: "memory");
}

__device__ __forceinline__ void load_lds16(const void* g, void* l) {
  __builtin_amdgcn_global_load_lds(
      (const __attribute__((address_space(1))) unsigned int*)g,
      (__attribute__((address_space(3))) unsigned int*)l, 16, 0, 0);
}

// ---------- dtype probe ----------
__global__ __launch_bounds__(64) void probe_kernel(
    const unsigned short* __restrict__ sequ, const unsigned* __restrict__ labu,
    int* __restrict__ flags)
{
  int t = threadIdx.x;
  int wild = 0;
#pragma unroll
  for (int i = 0; i < 4; i++) {
    unsigned short v = sequ[t + i * 64];
    int e = (v >> 7) & 0xFF;
    if (e < 90 || e > 160) wild++;
  }
  int nzodd = 0;
#pragma unroll
  for (int i = 0; i < 2; i++) {
    unsigned w = labu[(t + i * 64) * 2 + 1];
    if (w != 0) nzodd++;
  }
  for (int o = 32; o > 0; o >>= 1) {
    wild  += __shfl_down(wild, o);
    nzodd += __shfl_down(nzodd, o);
  }
  if (t == 0) {
    flags[0] = (wild > 32) ? 1 : 0;
    flags[1] = (nzodd == 0) ? 1 : 0;
  }
}

// ---------- seq -> bf16 ----------
__global__ __launch_bounds__(256) void conv_seq_kernel(
    const void* __restrict__ seq, bf16* __restrict__ seqb,
    const int* __restrict__ flags)
{
  int flag = flags[0];
  long row = blockIdx.x;
#pragma unroll
  for (int i = 0; i < 3; i++) {
    long e = row * Dd + threadIdx.x + i * 256;
    seqb[e] = __float2bfloat16(ldg_any(seq, e, flag));
  }
}

// ---------- generic convert to bf16 (Wih) ----------
__global__ __launch_bounds__(256) void convert_kernel(
    const void* __restrict__ src, bf16* __restrict__ dst, long n,
    const int* __restrict__ flags)
{
  int flag = flags[0];
  long i = (long)blockIdx.x * 256 + threadIdx.x;
  if (i < n) dst[i] = __float2bfloat16(ldg_any(src, i, flag));
}

// ---------- Qsmall[11][7][768] = relu(emb7 @ Wq + bq); grid (12, 11) ----------
__global__ __launch_bounds__(256) void smalls_kernel(
    const void* __restrict__ emb, const void* __restrict__ Wq,
    const void* __restrict__ bq, float* __restrict__ Qsmall,
    const int* __restrict__ flags)
{
  int flag = flags[0];
  __shared__ float embsh[7 * 768];
  __shared__ float psum[4][7][64];
  int z = blockIdx.y;
  int bx = blockIdx.x;
  int tid = threadIdx.x;
  int sub = tid >> 6, nl = tid & 63;
  for (int i = tid; i < 7 * 768; i += 256) embsh[i] = ldg_any(emb, i, flag);
  __syncthreads();
  int n = bx * 64 + nl;
  long base = (long)z * WSLICE;
  float acc[7] = {};
  int e0 = sub * 192;
  for (int e = e0; e < e0 + 192; e++) {
    float wv = ldg_any(Wq, base + (long)e * Dd + n, flag);
#pragma unroll
    for (int l = 0; l < 7; l++) acc[l] += embsh[l * 768 + e] * wv;
  }
#pragma unroll
  for (int l = 0; l < 7; l++) psum[sub][l][nl] = acc[l];
  __syncthreads();
  if (sub == 0) {
    float bv = ldg_any(bq, z * Dd + n, flag);
#pragma unroll
    for (int l = 0; l < 7; l++) {
      float v = psum[0][l][nl] + psum[1][l][nl] + psum[2][l][nl] + psum[3][l][nl] + bv;
      Qsmall[((long)z * 7 + l) * Dd + n] = fmaxf(v, 0.f);
    }
  }
}

// ---------- emb rows -> outsm[640+l] (bf16) + qmask7 ----------
__global__ __launch_bounds__(256) void emb_copy_kernel(
    const void* __restrict__ emb, bf16* __restrict__ outsm,
    float* __restrict__ qmask7, const int* __restrict__ flags)
{
  int flag = flags[0];
  int l = blockIdx.x;
  int t = threadIdx.x;
  float s = 0.f;
#pragma unroll
  for (int i = 0; i < 3; i++) {
    int e = t + i * 256;
    float v = ldg_any(emb, (long)l * Dd + e, flag);
    outsm[(long)(640 + l) * Dd + e] = __float2bfloat16(v);
    s += v;
  }
  for (int o = 32; o > 0; o >>= 1) s += __shfl_down(s, o);
  __shared__ float red[4];
  if ((t & 63) == 0) red[t >> 6] = s;
  __syncthreads();
  if (t == 0) {
    float tot = red[0] + red[1] + red[2] + red[3];
    qmask7[l] = (tot != 0.f) ? 1.f : 0.f;
  }
}

// ---------- transpose Wk/Wv branch slices to [N][K] bf16 ----------
__global__ __launch_bounds__(256) void transpose2_kernel(
    const void* __restrict__ Wk, const void* __restrict__ Wv,
    bf16* __restrict__ WT, const int* __restrict__ flags)
{
  int flag = flags[0];
  __shared__ float tile[32][33];
  int z = blockIdx.z;
  int m = z >> 1, wsel = z & 1;
  const void* src = wsel ? Wv : Wk;
  long off = (long)m * WSLICE;
  bf16* dst = WT + (long)z * WSLICE;
  int kk0 = blockIdx.y * 32, n0 = blockIdx.x * 32;
  int tx = threadIdx.x & 31, ty = threadIdx.x >> 5;
#pragma unroll
  for (int i = 0; i < 4; i++)
    tile[ty + i * 8][tx] = ldg_any(src, off + (long)(kk0 + ty + i * 8) * Dd + n0 + tx, flag);
  __syncthreads();
#pragma unroll
  for (int i = 0; i < 4; i++)
    dst[(long)(n0 + ty + i * 8) * Dd + kk0 + tx] = __float2bfloat16(tile[tx][ty + i * 8]);
}

// ---------- MFMA GEMM core: C = epi(scale*A@B^T) ----------
// cMode: 0=bf16, 2=fp32, 3=fp16, 5=fp16 transposed via LDS bounce (coalesced).
// cMode 5 REQUIRES As,Bs to be one contiguous 16KB block.
__device__ __forceinline__ void gemm_mfma_core(
    const bf16* __restrict__ Ab, long ldA,
    const bf16* __restrict__ Bbp, long ldB,
    bf16* As, bf16* Bs, int bm, int bn, int K,
    const void* bias, long bOff,
    void* C, long ldC, int cMode,
    float scale, int relu, int fflag)
{
  int tid = threadIdx.x;
  int lane = tid & 63, w = tid >> 6;
  int mo = (w & 1) * 64, no = (w >> 1) * 64;
  int l15 = lane & 15, q4 = lane >> 4;
  int gr = lane >> 2;
  int gs = (lane & 3) * 8;
  const bf16* aS0 = Ab + (long)(bm + w * 16 + gr) * ldA + gs;
  const bf16* aS1 = aS0 + 64 * ldA;
  const bf16* bS0 = Bbp + (long)(bn + w * 16 + gr) * ldB + gs;
  const bf16* bS1 = bS0 + 64 * ldB;
  bf16* aD0 = As + w * 512;
  bf16* aD1 = As + 2048 + w * 512;
  bf16* bD0 = Bs + w * 512;
  bf16* bD1 = Bs + 2048 + w * 512;

  f32x4 acc[4][4];
#pragma unroll
  for (int i = 0; i < 4; i++)
#pragma unroll
    for (int j = 0; j < 4; j++)
#pragma unroll
      for (int r = 0; r < 4; r++) acc[i][j][r] = 0.f;

  for (int k0 = 0; k0 < K; k0 += 32) {
    load_lds16(aS0, aD0);
    load_lds16(aS1, aD1);
    load_lds16(bS0, bD0);
    load_lds16(bS1, bD1);
    aS0 += 32; aS1 += 32; bS0 += 32; bS1 += 32;
    __syncthreads();
    short8 af[4], bfv[4];
#pragma unroll
    for (int i = 0; i < 4; i++)
      af[i] = *(const short8*)(As + (mo + i * 16 + l15) * 32 + q4 * 8);
#pragma unroll
    for (int j = 0; j < 4; j++)
      bfv[j] = *(const short8*)(Bs + (no + j * 16 + l15) * 32 + q4 * 8);
#pragma unroll
    for (int i = 0; i < 4; i++)
#pragma unroll
      for (int j = 0; j < 4; j++)
        acc[i][j] = __builtin_amdgcn_mfma_f32_16x16x32_bf16(af[i], bfv[j], acc[i][j], 0, 0, 0);
    __syncthreads();
  }

  float bsv[4];
#pragma unroll
  for (int j = 0; j < 4; j++) {
    int colg = bn + no + j * 16 + l15;
    bsv[j] = bias ? ldg_any(bias, bOff + colg, fflag) : 0.f;
  }

  if (cMode == 5) {
    unsigned short* tile = (unsigned short*)As;   // [32][136]
    int cl = (no >> 6) * 16 + l15;
#pragma unroll
    for (int j = 0; j < 4; j++) {
      __syncthreads();
#pragma unroll
      for (int i = 0; i < 4; i++) {
#pragma unroll
        for (int r = 0; r < 4; r++) {
          float v = acc[i][j][r] * scale + bsv[j];
          if (relu) v = fmaxf(v, 0.f);
          tile[cl * 136 + mo + i * 16 + q4 * 4 + r] = f2h(v);
        }
      }
      __syncthreads();
#pragma unroll
      for (int uu = 0; uu < 2; uu++) {
        int u = tid + uu * 256;
        int c = u >> 4, mseg = u & 15;
        int colg = bn + (c >> 4) * 64 + j * 16 + (c & 15);
        uint2 v0 = *(const uint2*)(tile + c * 136 + mseg * 8);
        uint2 v1 = *(const uint2*)(tile + c * 136 + mseg * 8 + 4);
        uint4 pk; pk.x = v0.x; pk.y = v0.y; pk.z = v1.x; pk.w = v1.y;
        *(uint4*)((unsigned short*)C + (long)colg * ldC + bm + mseg * 8) = pk;
      }
    }
    return;
  }

#pragma unroll
  for (int i = 0; i < 4; i++) {
#pragma unroll
    for (int j = 0; j < 4; j++) {
      int colg = bn + no + j * 16 + l15;
#pragma unroll
      for (int r = 0; r < 4; r++) {
        int rowg = bm + mo + i * 16 + q4 * 4 + r;
        float v = acc[i][j][r] * scale + bsv[j];
        if (relu) v = fmaxf(v, 0.f);
        long off2 = (long)rowg * ldC + colg;
        if (cMode == 2)      ((float*)C)[off2] = v;
        else if (cMode == 3) ((unsigned short*)C)[off2] = f2h(v);
        else                 ((bf16*)C)[off2] = __float2bfloat16(v);
      }
    }
  }
}

// ---------- K/V projections + seqW, z: 0..21 = m*2+{K,V}; 22,23 = seqW dir ----------
__global__ __launch_bounds__(256, 2) void proj_kernel(
    const bf16* __restrict__ seqb, const bf16* __restrict__ WT,
    const void* __restrict__ bk, const void* __restrict__ bv,
    const bf16* __restrict__ WihB, const void* __restrict__ bih,
    unsigned short* __restrict__ Kb, unsigned short* __restrict__ Vt,
    bf16* __restrict__ seqW, const int* __restrict__ flags)
{
  __shared__ __align__(16) bf16 smem[8192];   // contiguous As+Bs (cMode 5 needs this)
  bf16* As = smem;
  bf16* Bs = smem + 4096;
  int z = blockIdx.z;
  if (z < 22) {
    int m = z >> 1, wsel = z & 1;
    const bf16* B = WT + (long)z * WSLICE;
    if (wsel == 0) {
      gemm_mfma_core(seqb, Dd, B, Dd, As, Bs, blockIdx.y * 128, blockIdx.x * 128, Dd,
                     bk, (long)m * Dd, Kb + (long)m * 4096 * Dd, Dd, 3, 1.f, 1, flags[0]);
    } else {
      gemm_mfma_core(seqb, Dd, B, Dd, As, Bs, blockIdx.y * 128, blockIdx.x * 128, Dd,
                     bv, (long)m * Dd, Vt + (long)m * Dd * 4096, 4096, 5, 1.f, 1, flags[0]);
    }
  } else {
    int dir = z - 22;
    gemm_mfma_core(seqb, Dd, WihB + (long)dir * WSLICE, Dd, As, Bs,
                   blockIdx.y * 128, blockIdx.x * 128, Dd,
                   bih, (long)dir * Dd, seqW + (long)dir * 4096 * Dd, Dd, 0,
                   1.f, 0, flags[0]);
  }
}

// ---------- PVW = outsm(768 rows incl emb @640) @ Wih^T (fp32), z = dir ----------
__global__ __launch_bounds__(256, 2) void pvw_kernel(
    const bf16* __restrict__ outsm, const bf16* __restrict__ WihB,
    float* __restrict__ PVW, const int* __restrict__ flags)
{
  __shared__ __align__(16) bf16 As[4096];
  __shared__ __align__(16) bf16 Bs[4096];
  int dir = blockIdx.z;
  gemm_mfma_core(outsm, Dd, WihB + (long)dir * WSLICE, Dd, As, Bs,
                 blockIdx.y * 128, blockIdx.x * 128, Dd,
                 nullptr, 0, PVW + (long)dir * 768 * Dd, Dd, 2, 1.f, 0, flags[0]);
}

// ---------- fused scores+softmax+mask+PV per (k,b) ----------
__global__ __launch_bounds__(512, 2) void attn_kernel(
    const unsigned short* __restrict__ Kb, const unsigned short* __restrict__ Vt,
    const float* __restrict__ Qsmall, const float* __restrict__ qmask7,
    bf16* __restrict__ outsm, float scl)
{
  int blk = blockIdx.x;  // k*8+b
  int k = blk >> 3, b = blk & 7;
  int tid = threadIdx.x;
  int lane = tid & 63, w = tid >> 6;
  __shared__ unsigned qs[7][384];
  __shared__ unsigned short ash[7][512];
  __shared__ float wred[8][7];
  __shared__ float gred[7];
  __shared__ float finv[7];
  for (int i = tid; i < 7 * 384; i += 512) {
    int l = i / 384, e2 = i - l * 384;
    const float* qp = Qsmall + ((long)k * 7 + l) * Dd + 2 * e2;
    qs[l][e2] = packh2(qp[0], qp[1]);
  }
  __syncthreads();
  const uint4* Krow = (const uint4*)(Kb + ((long)k * 4096 + b * 512 + tid) * Dd);
  float sc[7] = {};
  for (int e8 = 0; e8 < 96; e8++) {
    uint4 kv = Krow[e8];
#pragma unroll
    for (int l = 0; l < 7; l++) {
      sc[l] = dot2u(qs[l][e8 * 4],     kv.x, sc[l]);
      sc[l] = dot2u(qs[l][e8 * 4 + 1], kv.y, sc[l]);
      sc[l] = dot2u(qs[l][e8 * 4 + 2], kv.z, sc[l]);
      sc[l] = dot2u(qs[l][e8 * 4 + 3], kv.w, sc[l]);
    }
  }
#pragma unroll
  for (int l = 0; l < 7; l++) sc[l] *= scl;
#pragma unroll
  for (int l = 0; l < 7; l++) {
    float v = sc[l];
    for (int o = 32; o > 0; o >>= 1) v = fmaxf(v, __shfl_down(v, o));
    if (lane == 0) wred[w][l] = v;
  }
  __syncthreads();
  if (tid < 7) {
    float m = wred[0][tid];
#pragma unroll
    for (int i = 1; i < 8; i++) m = fmaxf(m, wred[i][tid]);
    gred[tid] = m;
  }
  __syncthreads();
  float ev[7];
#pragma unroll
  for (int l = 0; l < 7; l++) {
    ev[l] = __expf(sc[l] - gred[l]);
    float v = ev[l];
    for (int o = 32; o > 0; o >>= 1) v += __shfl_down(v, o);
    if (lane == 0) wred[w][l] = v;
  }
  __syncthreads();
  if (tid < 7) {
    float s = 0.f;
#pragma unroll
    for (int i = 0; i < 8; i++) s += wred[i][tid];
    finv[tid] = qmask7[tid] / s;
  }
  __syncthreads();
#pragma unroll
  for (int l = 0; l < 7; l++) ash[l][tid] = f2h(ev[l] * finv[l]);
  __syncthreads();
  for (int rep = 0; rep < 2; rep++) {
    int n = tid + rep * 512;
    if (n >= Dd) break;
    const uint4* Vrow = (const uint4*)(Vt + ((long)k * Dd + n) * 4096 + b * 512);
    float acc[7] = {};
    for (int m8 = 0; m8 < 64; m8++) {
      uint4 vv = Vrow[m8];
#pragma unroll
      for (int l = 0; l < 7; l++) {
        const unsigned* ap = (const unsigned*)&ash[l][0];
        acc[l] = dot2u(ap[m8 * 4],     vv.x, acc[l]);
        acc[l] = dot2u(ap[m8 * 4 + 1], vv.y, acc[l]);
        acc[l] = dot2u(ap[m8 * 4 + 2], vv.z, acc[l]);
        acc[l] = dot2u(ap[m8 * 4 + 3], vv.w, acc[l]);
      }
    }
#pragma unroll
    for (int l = 0; l < 7; l++)
      outsm[((long)blk * 7 + l) * Dd + n] = __float2bfloat16(acc[l]);
  }
}

// ---------- GRU v7: R9 structure; NO_AGPR requests all-arch VGPR allocation
// (gfx950 VOP3P cannot source AGPRs — proven by R12 compile failure — so any
// AGPR residency costs one v_accvgpr_read per dot2) ----------
__global__ __launch_bounds__(512) WAVES22 NO_AGPR void gru_kernel(
    const bf16* __restrict__ seqW,   // [2][4096][768], includes bih
    const float* __restrict__ PVW,   // [2][768][768]; rows n*7+l and 640+l(emb)
    const void* __restrict__ labels,
    const void* __restrict__ Whh, const void* __restrict__ bhh,
    float* __restrict__ hbuf, const int* __restrict__ flags)
{
  int flag = flags[0], lflag = flags[1];
  int idx = blockIdx.x;
  int dir = idx / 88, n = idx - dir * 88;
  int b = n & 7;
  int tid = threadIdx.x;
  int q = tid & 3, cg = tid >> 2;
  int hi = q >> 1;
  int ch = cg + hi * 128;
  int r0 = ch, r1 = 256 + ch, r2 = 512 + ch;

  // 6 rows × 64-half k-quarter, packed fp16x2 -> 192 regs
  unsigned w[6][32];
#pragma unroll
  for (int s = 0; s < 6; s++) {
    int row = (s >> 1) * 256 + cg + (s & 1) * 128;
    long base = ((long)dir * Dd + row) * Hh + q * 64;
    if (flag) {
      const float4* s4 = (const float4*)((const float*)Whh + base);
#pragma unroll
      for (int i = 0; i < 16; i++) {
        float4 v = s4[i];
        w[s][2 * i]     = packh2(v.x, v.y);
        w[s][2 * i + 1] = packh2(v.z, v.w);
      }
    } else {
      const uint4* s4 = (const uint4*)((const bf16*)Whh + base);
#pragma unroll
      for (int i = 0; i < 8; i++) {
        uint4 v = s4[i];
        w[s][4 * i]     = packh2(blo(v.x), bhi(v.x));
        w[s][4 * i + 1] = packh2(blo(v.y), bhi(v.y));
        w[s][4 * i + 2] = packh2(blo(v.z), bhi(v.z));
        w[s][4 * i + 3] = packh2(blo(v.w), bhi(v.w));
      }
    }
  }
  float bh0 = ldg_any(bhh, dir * Dd + r0, flag);
  float bh1 = ldg_any(bhh, dir * Dd + r1, flag);
  float bh2 = ldg_any(bhh, dir * Dd + r2, flag);

  __shared__ float rowsh[7 * 768];
  __shared__ int labsh[512];
  __shared__ __align__(16) unsigned short hsh[2][4 * 72];

  for (int i = tid; i < 7 * 768; i += 512) {
    int l = i / 768, row = i - l * 768;
    rowsh[i] = PVW[((long)dir * 768 + n * 7 + l) * Dd + row]
             + PVW[((long)dir * 768 + 640 + l) * Dd + row];
  }
  labsh[tid] = lflag ? (int)((const long long*)labels)[b * 512 + tid]
                     : ((const int*)labels)[b * 512 + tid];
  if (tid < 288) { hsh[0][tid] = 0; hsh[1][tid] = 0; }
  __syncthreads();

  const unsigned short* swu = (const unsigned short*)seqW
                            + ((long)dir * 4096 + b * 512) * Dd;
  int t0 = dir ? 511 : 0, t1 = dir ? 510 : 1, t2 = dir ? 509 : 2;
  unsigned short xs00 = swu[(long)t0 * Dd + r0];
  unsigned short xs01 = swu[(long)t0 * Dd + r1];
  unsigned short xs02 = swu[(long)t0 * Dd + r2];
  unsigned short xs10 = swu[(long)t1 * Dd + r0];
  unsigned short xs11 = swu[(long)t1 * Dd + r1];
  unsigned short xs12 = swu[(long)t1 * Dd + r2];
  unsigned short xs20 = swu[(long)t2 * Dd + r0];
  unsigned short xs21 = swu[(long)t2 * Dd + r1];
  unsigned short xs22 = swu[(long)t2 * Dd + r2];

  float hprev = 0.f;
  int hwaddr = (ch >> 6) * 72 + (ch & 63);
  for (int tt = 0; tt < Ss; tt++) {
    int t = dir ? 511 - tt : tt;
    int ttp = (tt + 3 < Ss) ? tt + 3 : Ss - 1;
    int tp = dir ? 511 - ttp : ttp;
    unsigned short xp0 = swu[(long)tp * Dd + r0];
    unsigned short xp1 = swu[(long)tp * Dd + r1];
    unsigned short xp2 = swu[(long)tp * Dd + r2];
    int lab = labsh[t];
    const float* rs = rowsh + lab * 768;
    float xr = rs[r0] + b2f(xs00);
    float xz = rs[r1] + b2f(xs01);
    float xn = rs[r2] + b2f(xs02);
    const uint4* hq = (const uint4*)(hsh[tt & 1] + q * 72);
    float a[6] = {};
#pragma unroll
    for (int jj = 0; jj < 8; jj++) {
      uint4 hv = hq[jj];
#pragma unroll
      for (int s = 0; s < 6; s++) {
        a[s] = dot2u(w[s][4 * jj],     hv.x, a[s]);
        a[s] = dot2u(w[s][4 * jj + 1], hv.y, a[s]);
        a[s] = dot2u(w[s][4 * jj + 2], hv.z, a[s]);
        a[s] = dot2u(w[s][4 * jj + 3], hv.w, a[s]);
      }
    }
#pragma unroll
    for (int s = 0; s < 6; s++) a[s] = quad_sum(a[s]);
    float ar = hi ? a[1] : a[0];
    float az = hi ? a[3] : a[2];
    float an = hi ? a[5] : a[4];
    float rg = 1.f / (1.f + __expf(-(xr + ar + bh0)));
    float zg = 1.f / (1.f + __expf(-(xz + az + bh1)));
    float targ = xn + rg * (an + bh2);
    float e2 = __expf(2.f * targ);
    float ng = 1.f - 2.f / (e2 + 1.f);
    float hnew = (1.f - zg) * ng + zg * hprev;
    hprev = hnew;
    if ((q & 1) == 0) hsh[(tt + 1) & 1][hwaddr] = f2h(hnew);
    lds_barrier();
    xs00 = xs10; xs01 = xs11; xs02 = xs12;
    xs10 = xs20; xs11 = xs21; xs12 = xs22;
    xs20 = xp0;  xs21 = xp1;  xs22 = xp2;
  }
  if ((q & 1) == 0) hbuf[((long)(dir * 88 + n)) * Hh + ch] = hprev;
}

// ---------- final head ----------
__global__ __launch_bounds__(256) void head_kernel(
    const float* __restrict__ hbuf, const void* __restrict__ W1,
    const void* __restrict__ b1, void* __restrict__ out,
    const int* __restrict__ flags)
{
  int flag = flags[0];
  int n = blockIdx.x;
  int c = threadIdx.x;
  float v = hbuf[(long)n * Hh + c] * ldg_any(W1, c, flag)
          + hbuf[(long)(88 + n) * Hh + c] * ldg_any(W1, 256 + c, flag);
  for (int o = 32; o > 0; o >>= 1) v += __shfl_down(v, o);
  __shared__ float red[4];
  if ((c & 63) == 0) red[c >> 6] = v;
  __syncthreads();
  if (c == 0) {
    float s = red[0] + red[1] + red[2] + red[3] + ldg_any(b1, 0, flag);
    float sig = 1.f / (1.f + __expf(-s));
    int k = n / Bb, b = n - k * Bb;
    int o = b * NATT + k;
    if (flag) ((float*)out)[o] = sig;
    else      stf((bf16*)out + o, sig);
  }
}

extern "C" void kernel_launch(void* const* d_in, const int* in_sizes, int n_in,
                              void* d_out, int out_size, void* d_ws, size_t ws_size,
                              hipStream_t stream) {
  const void* labels = d_in[0];
  const void* seq  = d_in[1];
  const void* emb  = d_in[2];
  const void* Wq   = d_in[3];
  const void* bq   = d_in[4];
  const void* Wk   = d_in[5];
  const void* bk   = d_in[6];
  const void* Wv   = d_in[7];
  const void* bv   = d_in[8];
  const void* Wih  = d_in[9];
  const void* Whh  = d_in[10];
  const void* bih  = d_in[11];
  const void* bhh  = d_in[12];
  const void* W1   = d_in[13];
  const void* b1   = d_in[14];

  char* p = (char*)d_ws;
  size_t off = 0;
  auto alloc = [&](size_t bytes) -> void* {
    void* r = p + off; off += (bytes + 255) & ~(size_t)255; return r;
  };
  int*    flags  = (int*)alloc(2 * sizeof(int));
  bf16*   seqb   = (bf16*)alloc(4096UL * 768 * 2);
  float*  qmask7 = (float*)alloc(7 * 4);
  float*  Qsmall = (float*)alloc(11UL * 7 * 768 * 4);
  bf16*   WihB   = (bf16*)alloc(2UL * WSLICE * 2);
  bf16*   WT     = (bf16*)alloc(22UL * WSLICE * 2);
  unsigned short* Kb = (unsigned short*)alloc(11UL * 4096 * 768 * 2);
  unsigned short* Vt = (unsigned short*)alloc(11UL * 768 * 4096 * 2);
  bf16*   outsm  = (bf16*)alloc(768UL * 768 * 2);
  float*  PVW    = (float*)alloc(2UL * 768 * 768 * 4);
  bf16*   seqW   = (bf16*)alloc(2UL * 4096 * 768 * 2);
  float*  hbuf   = (float*)alloc(2UL * 88 * 256 * 4);
  if (off > ws_size) return;

  probe_kernel<<<1, 64, 0, stream>>>((const unsigned short*)seq,
                                     (const unsigned*)labels, flags);
  conv_seq_kernel<<<4096, 256, 0, stream>>>(seq, seqb, flags);
  convert_kernel<<<(int)((2 * WSLICE + 255) / 256), 256, 0, stream>>>(
      Wih, WihB, 2L * WSLICE, flags);
  smalls_kernel<<<dim3(12, 11), 256, 0, stream>>>(emb, Wq, bq, Qsmall, flags);
  emb_copy_kernel<<<7, 256, 0, stream>>>(emb, outsm, qmask7, flags);
  transpose2_kernel<<<dim3(24, 24, 22), 256, 0, stream>>>(Wk, Wv, WT, flags);
  proj_kernel<<<dim3(6, 32, 24), 256, 0, stream>>>(
      seqb, WT, bk, bv, WihB, bih, Kb, Vt, seqW, flags);
  const float scl = 1.f / sqrtf(768.f);
  attn_kernel<<<88, 512, 0, stream>>>(Kb, Vt, Qsmall, qmask7, outsm, scl);
  pvw_kernel<<<dim3(6, 6, 2), 256, 0, stream>>>(outsm, WihB, PVW, flags);
  gru_kernel<<<176, 512, 0, stream>>>(seqW, PVW, labels, Whh, bhh, hbuf, flags);
  head_kernel<<<88, 256, 0, stream>>>(hbuf, W1, b1, d_out, flags);
}